// Round 5
// baseline (366.824 us; speedup 1.0000x reference)
//
#include <hip/hip_runtime.h>
#include <hip/hip_bf16.h>

// GCN_simple: B=512 graphs x 128 nodes, FEAT=HID=512, OUT=10.
// R13: GEMMs identified as LDS-BW-bound (176KB/kt/CU vs 1242cyc MFMA).
// B operand now read DIRECT from global (W1t/W2t are per-XCD L2-resident,
// 512KB; per-lane 16B rows, 64B-aligned q-group segments; kt*64B folds
// into the 13-bit imm offset; single 32-bit voffset -> no VGPR growth).
// LDS traffic drops 55% -> loop becomes MFMA-bound; per-barrier DMA drain
// drops 24KB->8KB. B loads issued BEFORE next-tile A DMA so the compiler
// waits vmcnt(1) (keeps the A prefetch in flight) instead of draining.
// A staging (gload_lds dbuf) and all verified index/swizzle math unchanged.
// Dispatches: prep(+x->bf16) -> gemm1 -> gemm2 -> final_out.
// Fallback: R9 fused kernel if ws_size can't hold xb+H1 (~131MB).

typedef __attribute__((ext_vector_type(8))) short short8;
typedef __attribute__((ext_vector_type(4))) float f32x4;
typedef __attribute__((ext_vector_type(2))) unsigned int uint2v;

#define AS_G __attribute__((address_space(1)))
#define AS_L __attribute__((address_space(3)))

__device__ __forceinline__ void gload_lds16(const void* g, void* l) {
  __builtin_amdgcn_global_load_lds((const AS_G void*)g, (AS_L void*)l, 16, 0, 0);
}

// RNE fp32->bf16 (finite), packed: b -> high 16, a -> low 16.
__device__ __forceinline__ unsigned int pack2_bf16(float a, float b) {
  unsigned int ua = __float_as_uint(a);
  unsigned int ub = __float_as_uint(b);
  ua += 0x7FFFu + ((ua >> 16) & 1u);
  ub += 0x7FFFu + ((ub >> 16) & 1u);
  return (ua >> 16) | (ub & 0xFFFF0000u);
}

__device__ __forceinline__ unsigned short bf16_rne(float a) {
  unsigned int ua = __float_as_uint(a);
  ua += 0x7FFFu + ((ua >> 16) & 1u);
  return (unsigned short)(ua >> 16);
}

// ---------------------------------------------------------------------------
// gemm1: H1 = relu(agg(xb @ W1) + b1), bf16 out. Grid 1024 = 512 graphs x 2
// col-halves. Block 512 thr / 8 waves, tile 128x256, K=512 in 16 steps of 32.
// A (xb bf16) staged via gload_lds dbuf; B (W1t) read direct from L2.
// ---------------------------------------------------------------------------
__global__ __launch_bounds__(512, 4) void gemm1(
    const unsigned short* __restrict__ xb,    // [65536][512] bf16
    const __hip_bfloat16* __restrict__ W1t,   // [n][k] bf16
    const float* __restrict__ b1,
    unsigned short* __restrict__ H1)          // [65536][512] bf16
{
  // LDS: A dbuf 2x4096 elems [0,8192); scratch f32 redf[512]@8192, Sbuf[256]@9216
  __shared__ __align__(16) __hip_bfloat16 smem[9728];   // 19 KB

  const int t    = threadIdx.x;
  const int orig = blockIdx.x;
  const int wgid = (orig & 7) * 128 + (orig >> 3);   // XCD-chunked (1024%8==0)
  const int g    = wgid >> 1;          // graph / M-tile
  const int nb   = wgid & 1;           // col half (256 cols)

  const int wave = t >> 6;
  const int l    = t & 63;
  const int q    = l >> 4;
  const int r16  = l & 15;
  const int wm   = (wave & 1) * 64;
  const int wn   = (wave >> 1) * 64;   // 0,64,128,192

  // A staging (1 gload_lds/thread): u = t -> (arow = t>>2, slot = t&3)
  const int arow = t >> 2;
  const int slot = t & 3;
  const unsigned short* gaA = xb + (size_t)(g * 128 + arow) * 512 +
                              ((slot ^ ((arow >> 1) & 3)) << 3);

  // B direct-from-global per-lane element offset (row = nb*256+wn+j*16+r16,
  // k = kt*32 + q*8); j adds j*8192 elems, kt adds kt*32 (imm-foldable 64B).
  const int bvo = (nb * 256 + wn + r16) * 512 + q * 8;

  f32x4 acc[4][4];
#pragma unroll
  for (int i = 0; i < 4; ++i)
#pragma unroll
    for (int j = 0; j < 4; ++j)
      acc[i][j] = (f32x4)0.0f;

  // prologue: stage A kt=0
  gload_lds16(gaA, smem + wave * 512);

  for (int kt = 0; kt < 16; ++kt) {
    const int cur = kt & 1;
    const int nxt = cur ^ 1;
    __syncthreads();   // A(cur) staged & visible

    // B(cur) first (so the pre-MFMA wait can leave the A prefetch in flight)
    short8 bfr[4];
#pragma unroll
    for (int j = 0; j < 4; ++j)
      bfr[j] = *(const short8*)(const void*)(W1t + bvo + j * 8192 + kt * 32);

    if (kt < 15)
      gload_lds16(gaA + (kt + 1) * 32, smem + nxt * 4096 + wave * 512);

    short8 af[4];
#pragma unroll
    for (int i = 0; i < 4; ++i) {
      const int row = wm + i * 16 + r16;
      const int c   = (q ^ ((row >> 1) & 3)) << 3;
      af[i] = *(const short8*)(const void*)(smem + cur * 4096 + row * 32 + c);
    }
    __builtin_amdgcn_s_setprio(1);
#pragma unroll
    for (int i = 0; i < 4; ++i)
#pragma unroll
      for (int j = 0; j < 4; ++j)
        acc[i][j] = __builtin_amdgcn_mfma_f32_16x16x32_bf16(af[i], bfr[j], acc[i][j], 0, 0, 0);
    __builtin_amdgcn_s_setprio(0);
  }

  float* redf = (float*)(smem + 8192);    // 512 f32 (2 KB)
  float* Sbuf = (float*)(smem + 9216);    // 256 f32 (1 KB)
  const size_t hbase = (size_t)g * 128 * 512 + nb * 256;

  if (g == 0) {
    // column sums over all 128 rows (this block owns all of graph 0's rows)
    float sj[4];
#pragma unroll
    for (int j = 0; j < 4; ++j) {
      float a = 0.0f;
#pragma unroll
      for (int i = 0; i < 4; ++i)
#pragma unroll
        for (int r = 0; r < 4; ++r)
          a += acc[i][j][r];
      a += __shfl_xor(a, 16, 64);
      a += __shfl_xor(a, 32, 64);
      sj[j] = a;
    }
    __syncthreads();
    if (q == 0) {
#pragma unroll
      for (int j = 0; j < 4; ++j) redf[wave * 64 + j * 16 + r16] = sj[j];
    }
    __syncthreads();
    if (t < 256)
      Sbuf[t] = redf[(2 * (t >> 6)) * 64 + (t & 63)] +
                redf[(2 * (t >> 6) + 1) * 64 + (t & 63)];
    __syncthreads();
    float bvv[4], Svv[4];
#pragma unroll
    for (int j = 0; j < 4; ++j) {
      bvv[j] = b1[nb * 256 + wn + j * 16 + r16];
      Svv[j] = Sbuf[wn + j * 16 + r16];
    }
#pragma unroll
    for (int i = 0; i < 4; ++i)
#pragma unroll
      for (int r = 0; r < 4; ++r) {
        const int row = wm + i * 16 + q * 4 + r;
#pragma unroll
        for (int j = 0; j < 4; ++j) {
          const float v = fmaxf((Svv[j] + acc[i][j][r]) * (1.0f / 129.0f) + bvv[j], 0.0f);
          const float o = __shfl_xor(v, 1, 64);
          if ((r16 & 1) == 0)
            *(unsigned int*)(void*)(H1 + hbase + (size_t)row * 512 + wn + j * 16 + r16) =
                pack2_bf16(v, o);
        }
      }
  } else {
    float bvv[4];
#pragma unroll
    for (int j = 0; j < 4; ++j) bvv[j] = b1[nb * 256 + wn + j * 16 + r16];
#pragma unroll
    for (int i = 0; i < 4; ++i)
#pragma unroll
      for (int r = 0; r < 4; ++r) {
        const int row = wm + i * 16 + q * 4 + r;
#pragma unroll
        for (int j = 0; j < 4; ++j) {
          const float v = fmaxf(acc[i][j][r] + bvv[j], 0.0f);
          const float o = __shfl_xor(v, 1, 64);
          if ((r16 & 1) == 0)
            *(unsigned int*)(void*)(H1 + hbase + (size_t)row * 512 + wn + j * 16 + r16) =
                pack2_bf16(v, o);
        }
      }
  }
}

// ---------------------------------------------------------------------------
// gemm2: C2 = H1 @ W2; P[g][c] = (1/128) * sum_rows relu(agg(C2) + b2).
// Same geometry as gemm1; epilogue pools instead of writing H-matrix.
// ---------------------------------------------------------------------------
__global__ __launch_bounds__(512, 4) void gemm2(
    const unsigned short* __restrict__ H1,    // [65536][512] bf16
    const __hip_bfloat16* __restrict__ W2t,   // [n][k] bf16
    const float* __restrict__ b2,
    float* __restrict__ P)                    // [512][512] f32 (mean-pooled)
{
  __shared__ __align__(16) __hip_bfloat16 smem[9728];

  const int t    = threadIdx.x;
  const int orig = blockIdx.x;
  const int wgid = (orig & 7) * 128 + (orig >> 3);
  const int g    = wgid >> 1;
  const int nb   = wgid & 1;

  const int wave = t >> 6;
  const int l    = t & 63;
  const int q    = l >> 4;
  const int r16  = l & 15;
  const int wm   = (wave & 1) * 64;
  const int wn   = (wave >> 1) * 64;

  const int arow = t >> 2;
  const int slot = t & 3;
  const unsigned short* gaA = H1 + (size_t)(g * 128 + arow) * 512 +
                              ((slot ^ ((arow >> 1) & 3)) << 3);

  const int bvo = (nb * 256 + wn + r16) * 512 + q * 8;

  f32x4 acc[4][4];
#pragma unroll
  for (int i = 0; i < 4; ++i)
#pragma unroll
    for (int j = 0; j < 4; ++j)
      acc[i][j] = (f32x4)0.0f;

  gload_lds16(gaA, smem + wave * 512);

  for (int kt = 0; kt < 16; ++kt) {
    const int cur = kt & 1;
    const int nxt = cur ^ 1;
    __syncthreads();

    short8 bfr[4];
#pragma unroll
    for (int j = 0; j < 4; ++j)
      bfr[j] = *(const short8*)(const void*)(W2t + bvo + j * 8192 + kt * 32);

    if (kt < 15)
      gload_lds16(gaA + (kt + 1) * 32, smem + nxt * 4096 + wave * 512);

    short8 af[4];
#pragma unroll
    for (int i = 0; i < 4; ++i) {
      const int row = wm + i * 16 + r16;
      const int c   = (q ^ ((row >> 1) & 3)) << 3;
      af[i] = *(const short8*)(const void*)(smem + cur * 4096 + row * 32 + c);
    }
    __builtin_amdgcn_s_setprio(1);
#pragma unroll
    for (int i = 0; i < 4; ++i)
#pragma unroll
      for (int j = 0; j < 4; ++j)
        acc[i][j] = __builtin_amdgcn_mfma_f32_16x16x32_bf16(af[i], bfr[j], acc[i][j], 0, 0, 0);
    __builtin_amdgcn_s_setprio(0);
  }

  float* redf = (float*)(smem + 8192);    // 512 f32
  float* Sbuf = (float*)(smem + 9216);    // 256 f32

  float pj[4];
  if (g == 0) {
    float sj[4];
#pragma unroll
    for (int j = 0; j < 4; ++j) {
      float a = 0.0f;
#pragma unroll
      for (int i = 0; i < 4; ++i)
#pragma unroll
        for (int r = 0; r < 4; ++r)
          a += acc[i][j][r];
      a += __shfl_xor(a, 16, 64);
      a += __shfl_xor(a, 32, 64);
      sj[j] = a;
    }
    __syncthreads();
    if (q == 0) {
#pragma unroll
      for (int j = 0; j < 4; ++j) redf[wave * 64 + j * 16 + r16] = sj[j];
    }
    __syncthreads();
    if (t < 256)
      Sbuf[t] = redf[(2 * (t >> 6)) * 64 + (t & 63)] +
                redf[(2 * (t >> 6) + 1) * 64 + (t & 63)];
    __syncthreads();
#pragma unroll
    for (int j = 0; j < 4; ++j) {
      const int col = wn + j * 16 + r16;
      const float bv = b2[nb * 256 + col];
      const float Sv = Sbuf[col];
      float a = 0.0f;
#pragma unroll
      for (int i = 0; i < 4; ++i)
#pragma unroll
        for (int r = 0; r < 4; ++r)
          a += fmaxf((Sv + acc[i][j][r]) * (1.0f / 129.0f) + bv, 0.0f);
      a += __shfl_xor(a, 16, 64);
      a += __shfl_xor(a, 32, 64);
      pj[j] = a;
    }
    __syncthreads();   // Sbuf/redf reads done before redf reuse below
  } else {
#pragma unroll
    for (int j = 0; j < 4; ++j) {
      const float bv = b2[nb * 256 + wn + j * 16 + r16];
      float a = 0.0f;
#pragma unroll
      for (int i = 0; i < 4; ++i)
#pragma unroll
        for (int r = 0; r < 4; ++r)
          a += fmaxf(acc[i][j][r] + bv, 0.0f);
      a += __shfl_xor(a, 16, 64);
      a += __shfl_xor(a, 32, 64);
      pj[j] = a;
    }
    __syncthreads();
  }
  if (q == 0) {
#pragma unroll
    for (int j = 0; j < 4; ++j) redf[wave * 64 + j * 16 + r16] = pj[j];
  }
  __syncthreads();
  if (t < 256)
    P[(size_t)g * 512 + nb * 256 + t] =
        (redf[(2 * (t >> 6)) * 64 + (t & 63)] +
         redf[(2 * (t >> 6) + 1) * 64 + (t & 63)]) * (1.0f / 128.0f);
}

// out[m][:] = P[m][:] @ Wf + bfv
__global__ void final_out(const float* __restrict__ P,
                          const float* __restrict__ Wf,
                          const float* __restrict__ bfv,
                          float* __restrict__ out) {
  const int m = blockIdx.x;
  const int l = threadIdx.x;
  float acc[10];
#pragma unroll
  for (int o = 0; o < 10; ++o) acc[o] = 0.0f;
  for (int c = l; c < 512; c += 64) {
    const float p = P[m * 512 + c];
#pragma unroll
    for (int o = 0; o < 10; ++o) acc[o] += p * Wf[c * 10 + o];
  }
#pragma unroll
  for (int off = 32; off; off >>= 1)
#pragma unroll
    for (int o = 0; o < 10; ++o) acc[o] += __shfl_down(acc[o], off, 64);
  if (l == 0) {
#pragma unroll
    for (int o = 0; o < 10; ++o) out[m * 10 + o] = acc[o] + bfv[o];
  }
}

// ===========================================================================
// R9 fused kernel (verified) — fallback when workspace can't hold xb+H1.
// ===========================================================================
__global__ __launch_bounds__(1024) void fused_gcn(
    const float* __restrict__ x,
    const __hip_bfloat16* __restrict__ W1t,
    const __hip_bfloat16* __restrict__ W2t,
    const float* __restrict__ b1,
    const float* __restrict__ b2,
    const float* __restrict__ Wf,
    const float* __restrict__ bfv,
    float* __restrict__ out)
{
  __shared__ __align__(16) __hip_bfloat16 smem[81920];

  const int t  = threadIdx.x;
  const int g  = blockIdx.x;
  const int wave = t >> 6;
  const int l    = t & 63;
  const int q    = l >> 4;
  const int r16  = l & 15;
  const int wm   = (wave & 1) * 64;
  const int wn   = (wave >> 1) * 64;

  const int arow = t >> 3;
  const int kq   = t & 7;
  const float* ga = x + ((size_t)g * 128 + arow) * 512 + kq * 4;
  const int awoff = arow * 32 + (((kq >> 1) ^ ((arow >> 1) & 3)) << 3) + (kq & 1) * 4;

  const int brow = t >> 2;
  const int bgc  = (t & 3) ^ ((brow >> 1) & 3);
  const size_t boff = (size_t)brow * 512 + bgc * 8;
  const __hip_bfloat16* g1b0 = W1t + boff;
  const __hip_bfloat16* g1b1 = g1b0 + (size_t)256 * 512;

  f32x4 acc[4][4];
#pragma unroll
  for (int i = 0; i < 4; ++i)
#pragma unroll
    for (int j = 0; j < 4; ++j)
      acc[i][j] = (f32x4)0.0f;

  {
    f32x4 a0 = *(const f32x4*)(const void*)ga;
    gload_lds16(g1b0, smem + 49152 + wave * 512);
    gload_lds16(g1b1, smem + 49152 + 8192 + wave * 512);
    uint2v w;
    w[0] = pack2_bf16(a0[0], a0[1]);
    w[1] = pack2_bf16(a0[2], a0[3]);
    *(uint2v*)(void*)(smem + awoff) = w;
  }
  for (int kt = 0; kt < 16; ++kt) {
    const int cur = kt & 1;
    const int nxt = cur ^ 1;
    __syncthreads();

    f32x4 aN;
    if (kt < 15) {
      const int ko = (kt + 1) * 32;
      aN = *(const f32x4*)(const void*)(ga + ko);
      gload_lds16(g1b0 + ko, smem + 49152 + nxt * 16384 + wave * 512);
      gload_lds16(g1b1 + ko, smem + 49152 + nxt * 16384 + 8192 + wave * 512);
    }

    short8 af[4], bfr[4];
#pragma unroll
    for (int i = 0; i < 4; ++i) {
      const int row = wm + i * 16 + r16;
      const int c   = (q ^ ((row >> 1) & 3)) << 3;
      af[i] = *(const short8*)(const void*)(smem + cur * 4096 + row * 32 + c);
    }
#pragma unroll
    for (int j = 0; j < 4; ++j) {
      const int row = wn + j * 16 + r16;
      const int c   = (q ^ ((row >> 1) & 3)) << 3;
      bfr[j] = *(const short8*)(const void*)(smem + 49152 + cur * 16384 + row * 32 + c);
    }
#pragma unroll
    for (int i = 0; i < 4; ++i)
#pragma unroll
      for (int j = 0; j < 4; ++j)
        acc[i][j] = __builtin_amdgcn_mfma_f32_16x16x32_bf16(af[i], bfr[j], acc[i][j], 0, 0, 0);

    if (kt < 15) {
      uint2v w;
      w[0] = pack2_bf16(aN[0], aN[1]);
      w[1] = pack2_bf16(aN[2], aN[3]);
      *(uint2v*)(void*)(smem + nxt * 4096 + awoff) = w;
    }
  }
  __syncthreads();

  const __hip_bfloat16* g2b0 = W2t + boff;
  const __hip_bfloat16* g2b1 = g2b0 + (size_t)256 * 512;
  gload_lds16(g2b0, smem + 65536 + wave * 512);

  float* redf = (float*)(smem + 73728);
  float* Sbuf = (float*)(smem + 75776);

  if (g == 0) {
    float sj[4];
#pragma unroll
    for (int j = 0; j < 4; ++j) {
      float a = 0.0f;
#pragma unroll
      for (int i = 0; i < 4; ++i)
#pragma unroll
        for (int r = 0; r < 4; ++r)
          a += acc[i][j][r];
      a += __shfl_xor(a, 16, 64);
      a += __shfl_xor(a, 32, 64);
      sj[j] = a;
    }
    if (q == 0) {
#pragma unroll
      for (int j = 0; j < 4; ++j) redf[wave * 64 + j * 16 + r16] = sj[j];
    }
    __syncthreads();
    if (t < 512)
      Sbuf[t] = redf[((t >> 6) * 2) * 64 + (t & 63)] +
                redf[((t >> 6) * 2 + 1) * 64 + (t & 63)];
    __syncthreads();
#pragma unroll
    for (int j = 0; j < 4; ++j) {
      const int col = wn + j * 16 + r16;
      const float bv = b1[col];
      const float Sv = Sbuf[col];
#pragma unroll
      for (int i = 0; i < 4; ++i)
#pragma unroll
        for (int r = 0; r < 4; ++r) {
          const int row = wm + i * 16 + q * 4 + r;
          const float v = fmaxf((Sv + acc[i][j][r]) * (1.0f / 129.0f) + bv, 0.0f);
          const float o = __shfl_xor(v, 1, 64);
          if ((r16 & 1) == 0) {
            const int sl = (col >> 3) ^ (row & 7);
            *(unsigned int*)(void*)(smem + row * 512 + sl * 8 + (col & 7)) = pack2_bf16(v, o);
          }
        }
    }
  } else {
#pragma unroll
    for (int j = 0; j < 4; ++j) {
      const int col = wn + j * 16 + r16;
      const float bv = b1[col];
#pragma unroll
      for (int i = 0; i < 4; ++i)
#pragma unroll
        for (int r = 0; r < 4; ++r) {
          const int row = wm + i * 16 + q * 4 + r;
          const float v = fmaxf(acc[i][j][r] + bv, 0.0f);
          const float o = __shfl_xor(v, 1, 64);
          if ((r16 & 1) == 0) {
            const int sl = (col >> 3) ^ (row & 7);
            *(unsigned int*)(void*)(smem + row * 512 + sl * 8 + (col & 7)) = pack2_bf16(v, o);
          }
        }
    }
  }

#pragma unroll
  for (int i = 0; i < 4; ++i)
#pragma unroll
    for (int j = 0; j < 4; ++j)
      acc[i][j] = (f32x4)0.0f;

  for (int kt = 0; kt < 16; ++kt) {
    __syncthreads();
    gload_lds16(g2b1 + kt * 32, smem + 73728 + wave * 512);
    if (wave < 8) {
      short8 af[4], bfr[4];
#pragma unroll
      for (int i = 0; i < 4; ++i) {
        const int row = wm + i * 16 + r16;
        const int sl  = (kt * 4 + q) ^ (row & 7);
        af[i] = *(const short8*)(const void*)(smem + row * 512 + sl * 8);
      }
#pragma unroll
      for (int j = 0; j < 4; ++j) {
        const int row = wn + j * 16 + r16;
        const int c   = (q ^ ((row >> 1) & 3)) << 3;
        bfr[j] = *(const short8*)(const void*)(smem + 65536 + row * 32 + c);
      }
      __builtin_amdgcn_s_setprio(1);
#pragma unroll
      for (int i = 0; i < 4; ++i)
#pragma unroll
        for (int j = 0; j < 4; ++j)
          acc[i][j] = __builtin_amdgcn_mfma_f32_16x16x32_bf16(af[i], bfr[j], acc[i][j], 0, 0, 0);
      __builtin_amdgcn_s_setprio(0);
    }
    __syncthreads();
    if (kt < 15)
      gload_lds16(g2b0 + (kt + 1) * 32, smem + 65536 + wave * 512);
    if (wave >= 8) {
      short8 af[4], bfr[4];
#pragma unroll
      for (int i = 0; i < 4; ++i) {
        const int row = wm + i * 16 + r16;
        const int sl  = (kt * 4 + q) ^ (row & 7);
        af[i] = *(const short8*)(const void*)(smem + row * 512 + sl * 8);
      }
#pragma unroll
      for (int j = 0; j < 4; ++j) {
        const int row = wn + j * 16 + r16;
        const int c   = (q ^ ((row >> 1) & 3)) << 3;
        bfr[j] = *(const short8*)(const void*)(smem + 65536 + row * 32 + c);
      }
      __builtin_amdgcn_s_setprio(1);
#pragma unroll
      for (int i = 0; i < 4; ++i)
#pragma unroll
        for (int j = 0; j < 4; ++j)
          acc[i][j] = __builtin_amdgcn_mfma_f32_16x16x32_bf16(af[i], bfr[j], acc[i][j], 0, 0, 0);
      __builtin_amdgcn_s_setprio(0);
    }
  }
  __syncthreads();

  float pj[4];
  if (g == 0) {
    float sj[4];
#pragma unroll
    for (int j = 0; j < 4; ++j) {
      float a = 0.0f;
#pragma unroll
      for (int i = 0; i < 4; ++i)
#pragma unroll
        for (int r = 0; r < 4; ++r)
          a += acc[i][j][r];
      a += __shfl_xor(a, 16, 64);
      a += __shfl_xor(a, 32, 64);
      sj[j] = a;
    }
    if (q == 0) {
#pragma unroll
      for (int j = 0; j < 4; ++j) redf[wave * 64 + j * 16 + r16] = sj[j];
    }
    __syncthreads();
    if (t < 512)
      Sbuf[t] = redf[((t >> 6) * 2) * 64 + (t & 63)] +
                redf[((t >> 6) * 2 + 1) * 64 + (t & 63)];
    __syncthreads();
#pragma unroll
    for (int j = 0; j < 4; ++j) {
      const float bv = b2[wn + j * 16 + r16];
      const float Sv = Sbuf[wn + j * 16 + r16];
      float a = 0.0f;
#pragma unroll
      for (int i = 0; i < 4; ++i)
#pragma unroll
        for (int r = 0; r < 4; ++r)
          a += fmaxf((Sv + acc[i][j][r]) * (1.0f / 129.0f) + bv, 0.0f);
      a += __shfl_xor(a, 16, 64);
      a += __shfl_xor(a, 32, 64);
      pj[j] = a;
    }
  } else {
#pragma unroll
    for (int j = 0; j < 4; ++j) {
      const float bv = b2[wn + j * 16 + r16];
      float a = 0.0f;
#pragma unroll
      for (int i = 0; i < 4; ++i)
#pragma unroll
        for (int r = 0; r < 4; ++r)
          a += fmaxf(acc[i][j][r] + bv, 0.0f);
      a += __shfl_xor(a, 16, 64);
      a += __shfl_xor(a, 32, 64);
      pj[j] = a;
    }
  }
  if (q == 0) {
#pragma unroll
    for (int j = 0; j < 4; ++j) redf[wave * 64 + j * 16 + r16] = pj[j];
  }
  __syncthreads();
  if (t < 512)
    Sbuf[t] =
        (redf[((t >> 6) * 2) * 64 + (t & 63)] +
         redf[((t >> 6) * 2 + 1) * 64 + (t & 63)]) * (1.0f / 128.0f);
  __syncthreads();

  if (wave < 10) {
    float s = 0.0f;
    for (int c = l; c < 512; c += 64) s += Sbuf[c] * Wf[c * 10 + wave];
#pragma unroll
    for (int off = 32; off; off >>= 1) s += __shfl_down(s, off, 64);
    if (l == 0) out[(size_t)g * 10 + wave] = s + bfv[wave];
  }
}

// prep: blocks 0..511 transpose W1/W2 -> bf16 [n][k]; blocks 512..1023 fold
// Wf = W3@Wlin, bfv = b3@Wlin + blin; blocks 1024.. convert x -> xb bf16.
__global__ __launch_bounds__(1024) void prep(
    const float* __restrict__ W1, const float* __restrict__ W2,
    unsigned short* __restrict__ W1t, unsigned short* __restrict__ W2t,
    const float* __restrict__ W3, const float* __restrict__ Wlin,
    const float* __restrict__ b3, const float* __restrict__ blin,
    float* __restrict__ Wf, float* __restrict__ bfv,
    const float* __restrict__ x, unsigned short* __restrict__ xb) {
  const int b = blockIdx.x;
  if (b < 512) {
    __shared__ float tile[32][33];
    const int z  = b >> 8;
    const int by = (b >> 4) & 15;
    const int bx = b & 15;
    const float* W = z ? W2 : W1;
    unsigned short* Wt = z ? W2t : W1t;
    const int tx = threadIdx.x & 31;
    const int ty = threadIdx.x >> 5;
    tile[ty][tx] = W[(by * 32 + ty) * 512 + bx * 32 + tx];
    __syncthreads();
    Wt[(bx * 32 + ty) * 512 + by * 32 + tx] = bf16_rne(tile[tx][ty]);
  } else if (b < 1024) {
    const int c = b - 512;
    const int l = threadIdx.x;
    if (l < 64) {
      float acc[10];
#pragma unroll
      for (int o = 0; o < 10; ++o) acc[o] = 0.0f;
      for (int n = l; n < 512; n += 64) {
        const float wv = W3[c * 512 + n];
#pragma unroll
        for (int o = 0; o < 10; ++o) acc[o] += wv * Wlin[n * 10 + o];
      }
#pragma unroll
      for (int off = 32; off; off >>= 1)
#pragma unroll
        for (int o = 0; o < 10; ++o) acc[o] += __shfl_down(acc[o], off, 64);
      if (l == 0) {
#pragma unroll
        for (int o = 0; o < 10; ++o) Wf[c * 10 + o] = acc[o];
      }
      if (c < 10) {
        float s = 0.0f;
        for (int k = l; k < 512; k += 64) s += b3[k] * Wlin[k * 10 + c];
#pragma unroll
        for (int off = 32; off; off >>= 1) s += __shfl_down(s, off, 64);
        if (l == 0) bfv[c] = s + blin[c];
      }
    }
  } else {
    // x -> xb (bf16 RNE), 8192 f32 per block, fully coalesced 16B/8B lanes
    const size_t base = (size_t)(b - 1024) * 8192;
    const int tt = threadIdx.x;
#pragma unroll
    for (int jj = 0; jj < 2; ++jj) {
      const size_t off = base + (size_t)jj * 4096 + (size_t)tt * 4;
      const f32x4 v = *(const f32x4*)(const void*)(x + off);
      uint2v w;
      w[0] = pack2_bf16(v[0], v[1]);
      w[1] = pack2_bf16(v[2], v[3]);
      *(uint2v*)(void*)(xb + off) = w;
    }
  }
}

extern "C" void kernel_launch(void* const* d_in, const int* in_sizes, int n_in,
                              void* d_out, int out_size, void* d_ws, size_t ws_size,
                              hipStream_t stream) {
  const float* x    = (const float*)d_in[0];
  const float* W1   = (const float*)d_in[1];
  const float* b1   = (const float*)d_in[2];
  const float* W2   = (const float*)d_in[3];
  const float* b2   = (const float*)d_in[4];
  const float* W3   = (const float*)d_in[5];
  const float* b3   = (const float*)d_in[6];
  const float* Wlin = (const float*)d_in[7];
  const float* blin = (const float*)d_in[8];
  float* out = (float*)d_out;

  char* ws = (char*)d_ws;
  unsigned short* W1t = (unsigned short*)ws;                 // 512 KB
  unsigned short* W2t = W1t + 512 * 512;                     // 512 KB
  float* Wf           = (float*)(W2t + 512 * 512);           // 20 KB
  float* bfv          = Wf + 512 * 10;                       // 64 B
  float* P            = bfv + 16;                            // 1 MB
  unsigned short* H1  = (unsigned short*)(P + 512 * 512);    // 64 MB
  unsigned short* xb  = H1 + (size_t)65536 * 512;            // 64 MB

  const size_t need = (size_t)512 * 512 * 2 * 2 +            // W1t, W2t
                      (512 * 10 + 16 + 512 * 512) * 4 +      // Wf, bfv, P
                      (size_t)65536 * 512 * 2 * 2;           // H1, xb

  const bool split = ws_size >= need;

  prep<<<split ? 5120 : 1024, 1024, 0, stream>>>(
      W1, W2, W1t, W2t, W3, Wlin, b3, blin, Wf, bfv, x, xb);

  if (split) {
    gemm1<<<1024, 512, 0, stream>>>(xb, (const __hip_bfloat16*)W1t, b1, H1);
    gemm2<<<1024, 512, 0, stream>>>(H1, (const __hip_bfloat16*)W2t, b2, P);
    final_out<<<512, 64, 0, stream>>>(P, Wf, bfv, out);
  } else {
    fused_gcn<<<512, 1024, 0, stream>>>(
        x, (const __hip_bfloat16*)W1t, (const __hip_bfloat16*)W2t, b1, b2, Wf, bfv, out);
  }
}

// Round 6
// 294.297 us; speedup vs baseline: 1.2464x; 1.2464x over previous
//
#include <hip/hip_runtime.h>
#include <hip/hip_bf16.h>

// GCN_simple: B=512 graphs x 128 nodes, FEAT=HID=512, OUT=10.
// R14: split design, two changes vs R12/R13:
// (1) B back to gload_lds (R13's B-direct regressed: latency exposed).
// (2) 3-buffer rotation with raw s_barrier + COUNTED vmcnt (T4): per kt,
//     wait only for loads issued a full iteration ago (already landed);
//     this kt's prefetch crosses the barrier in flight. Replaces
//     __syncthreads' vmcnt(0) drain that exposed L2/HBM latency every kt.
// (3) gemm1 reads A DIRECT from x (f32) -> regs -> pack -> ds_write
//     (issued one kt ahead, packed the next kt). Kills xb + xconv
//     (-30-40us prep, -128MB traffic). Pack path + swizzle identical to
//     the proven fused-kernel staging family.
// LDS per gemm block: 3 bufs x (A 8KB + B 16KB) = 72KB + 3KB scratch ->
// 75KB -> 2 blocks/CU. All fragment/epilogue math verbatim from R12.
// Dispatches: prep -> gemm1 -> gemm2 -> final_out. Fallback: R9 fused.

typedef __attribute__((ext_vector_type(8))) short short8;
typedef __attribute__((ext_vector_type(4))) float f32x4;
typedef __attribute__((ext_vector_type(2))) unsigned int uint2v;
typedef __attribute__((ext_vector_type(4))) unsigned int uint4v;

#define AS_G __attribute__((address_space(1)))
#define AS_L __attribute__((address_space(3)))

__device__ __forceinline__ void gload_lds16(const void* g, void* l) {
  __builtin_amdgcn_global_load_lds((const AS_G void*)g, (AS_L void*)l, 16, 0, 0);
}

#define FENCE_BARRIER()                      \
  do {                                       \
    asm volatile("" ::: "memory");           \
    __builtin_amdgcn_s_barrier();            \
    asm volatile("" ::: "memory");           \
  } while (0)

// RNE fp32->bf16 (finite), packed: b -> high 16, a -> low 16.
__device__ __forceinline__ unsigned int pack2_bf16(float a, float b) {
  unsigned int ua = __float_as_uint(a);
  unsigned int ub = __float_as_uint(b);
  ua += 0x7FFFu + ((ua >> 16) & 1u);
  ub += 0x7FFFu + ((ub >> 16) & 1u);
  return (ua >> 16) | (ub & 0xFFFF0000u);
}

__device__ __forceinline__ unsigned short bf16_rne(float a) {
  unsigned int ua = __float_as_uint(a);
  ua += 0x7FFFu + ((ua >> 16) & 1u);
  return (unsigned short)(ua >> 16);
}

// ---------------------------------------------------------------------------
// gemm1: H1 = relu(agg(x @ W1) + b1), bf16 out. Grid 1024 = 512 graphs x 2
// col halves. Block 512 thr / 8 waves, tile 128x256, 16 kt of K=32.
// A: f32 from x, reg-staged 1 kt ahead (pack+ds_write next kt).
// B: W1t bf16 via gload_lds. 3-buffer rotation, counted vmcnt.
// ---------------------------------------------------------------------------
__global__ __launch_bounds__(512, 4) void gemm1(
    const float* __restrict__ x,
    const __hip_bfloat16* __restrict__ W1t,   // [n][k] bf16
    const float* __restrict__ b1,
    unsigned short* __restrict__ H1)          // [65536][512] bf16
{
  // 3 bufs x 12288 elems (A [0,4096), B [4096,12288)) + scratch @36864
  __shared__ __align__(16) __hip_bfloat16 smem[38400];   // 75 KB

  const int t    = threadIdx.x;
  const int orig = blockIdx.x;
  const int wgid = (orig & 7) * 128 + (orig >> 3);   // XCD-chunked
  const int g    = wgid >> 1;
  const int nb   = wgid & 1;

  const int wave = t >> 6;
  const int l    = t & 63;
  const int q    = l >> 4;
  const int r16  = l & 15;
  const int wm   = (wave & 1) * 64;
  const int wn   = (wave >> 1) * 64;

  // A source (f32): thread (arow=t>>2, slot=t&3) loads the 8 f32 whose bf16
  // image lands at LDS slot (t&3) -> source chunk = slot ^ sw(row).
  const int arow = t >> 2;
  const int slot = t & 3;
  const int achk = slot ^ ((arow >> 1) & 3);
  const float* gx = x + (size_t)(g * 128 + arow) * 512 + achk * 8;

  // B staging (2 gload_lds issues), verbatim R12
  const int nrow0 = t >> 2;
  const int nrow1 = 128 + (t >> 2);
  const __hip_bfloat16* gb0 = W1t + (size_t)(nb * 256 + nrow0) * 512 +
                              ((slot ^ ((nrow0 >> 1) & 3)) << 3);
  const __hip_bfloat16* gb1 = W1t + (size_t)(nb * 256 + nrow1) * 512 +
                              ((slot ^ ((nrow1 >> 1) & 3)) << 3);

  f32x4 acc[4][4];
#pragma unroll
  for (int i = 0; i < 4; ++i)
#pragma unroll
    for (int j = 0; j < 4; ++j)
      acc[i][j] = (f32x4)0.0f;

  int u0 = 0, u1 = 12288, u2 = 24576;   // cur / next / stage-target bases

  f32x4 pA0, pA1;
  // ---- prologue: buf0 (kt0) complete, kt1 in flight ----
  pA0 = *(const f32x4*)(const void*)gx;          // A kt0
  pA1 = *(const f32x4*)(const void*)(gx + 4);
  gload_lds16(gb0, smem + u0 + 4096 + wave * 512);   // B kt0
  gload_lds16(gb1, smem + u0 + 8192 + wave * 512);
  {
    uint4v w;
    w[0] = pack2_bf16(pA0[0], pA0[1]);
    w[1] = pack2_bf16(pA0[2], pA0[3]);
    w[2] = pack2_bf16(pA1[0], pA1[1]);
    w[3] = pack2_bf16(pA1[2], pA1[3]);
    *(uint4v*)(void*)(smem + u0 + t * 8) = w;    // waits A-kt0 (vmcnt), not B
  }
  pA0 = *(const f32x4*)(const void*)(gx + 32);   // A kt1
  pA1 = *(const f32x4*)(const void*)(gx + 36);
  gload_lds16(gb0 + 32, smem + u1 + 4096 + wave * 512);   // B kt1
  gload_lds16(gb1 + 32, smem + u1 + 8192 + wave * 512);
  asm volatile("s_waitcnt vmcnt(4)" ::: "memory");   // B-kt0 landed; kt1 in flight
  asm volatile("s_waitcnt lgkmcnt(0)" ::: "memory"); // A-kt0 ds_write visible
  FENCE_BARRIER();

  for (int kt = 0; kt < 16; ++kt) {
    // 1. pack A(kt+1) (loads issued last iter -> landed; compiler waits vmcnt(2))
    if (kt < 15) {
      uint4v w;
      w[0] = pack2_bf16(pA0[0], pA0[1]);
      w[1] = pack2_bf16(pA0[2], pA0[3]);
      w[2] = pack2_bf16(pA1[0], pA1[1]);
      w[3] = pack2_bf16(pA1[2], pA1[3]);
      *(uint4v*)(void*)(smem + u1 + t * 8) = w;
    }
    // 2. issue kt+2 (A f32 loads + B DMA) into stage-target buffer
    if (kt < 14) {
      const int ko = (kt + 2) * 32;
      pA0 = *(const f32x4*)(const void*)(gx + ko);
      pA1 = *(const f32x4*)(const void*)(gx + ko + 4);
      gload_lds16(gb0 + ko, smem + u2 + 4096 + wave * 512);
      gload_lds16(gb1 + ko, smem + u2 + 8192 + wave * 512);
      // 3. B(kt+1) landed; kt+2's 4 ops stay in flight across the barrier
      asm volatile("s_waitcnt vmcnt(4)" ::: "memory");
    } else {
      asm volatile("s_waitcnt vmcnt(0)" ::: "memory");
    }
    // 4. consume buf[kt%3]
    short8 af[4], bfr[4];
#pragma unroll
    for (int i = 0; i < 4; ++i) {
      const int row = wm + i * 16 + r16;
      const int c   = (q ^ ((row >> 1) & 3)) << 3;
      af[i] = *(const short8*)(const void*)(smem + u0 + row * 32 + c);
    }
#pragma unroll
    for (int j = 0; j < 4; ++j) {
      const int row = wn + j * 16 + r16;
      const int c   = (q ^ ((row >> 1) & 3)) << 3;
      bfr[j] = *(const short8*)(const void*)(smem + u0 + 4096 + row * 32 + c);
    }
    __builtin_amdgcn_s_setprio(1);
#pragma unroll
    for (int i = 0; i < 4; ++i)
#pragma unroll
      for (int j = 0; j < 4; ++j)
        acc[i][j] = __builtin_amdgcn_mfma_f32_16x16x32_bf16(af[i], bfr[j], acc[i][j], 0, 0, 0);
    __builtin_amdgcn_s_setprio(0);

    if (kt < 15) {
      asm volatile("s_waitcnt lgkmcnt(0)" ::: "memory");  // step-1 ds_writes visible
      FENCE_BARRIER();
    }
    const int tmp = u0; u0 = u1; u1 = u2; u2 = tmp;
  }
  __syncthreads();   // buffers dead -> scratch

  float* redf = (float*)(smem + 36864);   // 512 f32
  float* Sbuf = (float*)(smem + 37888);   // 256 f32
  const size_t hbase = (size_t)g * 128 * 512 + nb * 256;

  if (g == 0) {
    float sj[4];
#pragma unroll
    for (int j = 0; j < 4; ++j) {
      float a = 0.0f;
#pragma unroll
      for (int i = 0; i < 4; ++i)
#pragma unroll
        for (int r = 0; r < 4; ++r)
          a += acc[i][j][r];
      a += __shfl_xor(a, 16, 64);
      a += __shfl_xor(a, 32, 64);
      sj[j] = a;
    }
    __syncthreads();
    if (q == 0) {
#pragma unroll
      for (int j = 0; j < 4; ++j) redf[wave * 64 + j * 16 + r16] = sj[j];
    }
    __syncthreads();
    if (t < 256)
      Sbuf[t] = redf[(2 * (t >> 6)) * 64 + (t & 63)] +
                redf[(2 * (t >> 6) + 1) * 64 + (t & 63)];
    __syncthreads();
    float bvv[4], Svv[4];
#pragma unroll
    for (int j = 0; j < 4; ++j) {
      bvv[j] = b1[nb * 256 + wn + j * 16 + r16];
      Svv[j] = Sbuf[wn + j * 16 + r16];
    }
#pragma unroll
    for (int i = 0; i < 4; ++i)
#pragma unroll
      for (int r = 0; r < 4; ++r) {
        const int row = wm + i * 16 + q * 4 + r;
#pragma unroll
        for (int j = 0; j < 4; ++j) {
          const float v = fmaxf((Svv[j] + acc[i][j][r]) * (1.0f / 129.0f) + bvv[j], 0.0f);
          const float o = __shfl_xor(v, 1, 64);
          if ((r16 & 1) == 0)
            *(unsigned int*)(void*)(H1 + hbase + (size_t)row * 512 + wn + j * 16 + r16) =
                pack2_bf16(v, o);
        }
      }
  } else {
    float bvv[4];
#pragma unroll
    for (int j = 0; j < 4; ++j) bvv[j] = b1[nb * 256 + wn + j * 16 + r16];
#pragma unroll
    for (int i = 0; i < 4; ++i)
#pragma unroll
      for (int r = 0; r < 4; ++r) {
        const int row = wm + i * 16 + q * 4 + r;
#pragma unroll
        for (int j = 0; j < 4; ++j) {
          const float v = fmaxf(acc[i][j][r] + bvv[j], 0.0f);
          const float o = __shfl_xor(v, 1, 64);
          if ((r16 & 1) == 0)
            *(unsigned int*)(void*)(H1 + hbase + (size_t)row * 512 + wn + j * 16 + r16) =
                pack2_bf16(v, o);
        }
      }
  }
}

// ---------------------------------------------------------------------------
// gemm2: C2 = H1 @ W2; P[g][c] = (1/128) * sum_rows relu(agg(C2) + b2).
// A (H1 bf16) + B both via gload_lds; 3-buffer rotation, counted vmcnt.
// ---------------------------------------------------------------------------
__global__ __launch_bounds__(512, 4) void gemm2(
    const unsigned short* __restrict__ H1,    // [65536][512] bf16
    const __hip_bfloat16* __restrict__ W2t,   // [n][k] bf16
    const float* __restrict__ b2,
    float* __restrict__ P)                    // [512][512] f32 (mean-pooled)
{
  __shared__ __align__(16) __hip_bfloat16 smem[38400];

  const int t    = threadIdx.x;
  const int orig = blockIdx.x;
  const int wgid = (orig & 7) * 128 + (orig >> 3);
  const int g    = wgid >> 1;
  const int nb   = wgid & 1;

  const int wave = t >> 6;
  const int l    = t & 63;
  const int q    = l >> 4;
  const int r16  = l & 15;
  const int wm   = (wave & 1) * 64;
  const int wn   = (wave >> 1) * 64;

  const int arow = t >> 2;
  const int slot = t & 3;
  const unsigned short* gaA = H1 + (size_t)(g * 128 + arow) * 512 +
                              ((slot ^ ((arow >> 1) & 3)) << 3);
  const int nrow0 = t >> 2;
  const int nrow1 = 128 + (t >> 2);
  const __hip_bfloat16* gb0 = W2t + (size_t)(nb * 256 + nrow0) * 512 +
                              ((slot ^ ((nrow0 >> 1) & 3)) << 3);
  const __hip_bfloat16* gb1 = W2t + (size_t)(nb * 256 + nrow1) * 512 +
                              ((slot ^ ((nrow1 >> 1) & 3)) << 3);

  f32x4 acc[4][4];
#pragma unroll
  for (int i = 0; i < 4; ++i)
#pragma unroll
    for (int j = 0; j < 4; ++j)
      acc[i][j] = (f32x4)0.0f;

  int u0 = 0, u1 = 12288, u2 = 24576;

  // prologue: buf0 complete, buf1 in flight
  gload_lds16(gaA,      smem + u0 + wave * 512);
  gload_lds16(gb0,      smem + u0 + 4096 + wave * 512);
  gload_lds16(gb1,      smem + u0 + 8192 + wave * 512);
  gload_lds16(gaA + 32, smem + u1 + wave * 512);
  gload_lds16(gb0 + 32, smem + u1 + 4096 + wave * 512);
  gload_lds16(gb1 + 32, smem + u1 + 8192 + wave * 512);
  asm volatile("s_waitcnt vmcnt(3)" ::: "memory");   // buf0 landed
  FENCE_BARRIER();

  for (int kt = 0; kt < 16; ++kt) {
    if (kt < 14) {
      const int ko = (kt + 2) * 32;
      gload_lds16(gaA + ko, smem + u2 + wave * 512);
      gload_lds16(gb0 + ko, smem + u2 + 4096 + wave * 512);
      gload_lds16(gb1 + ko, smem + u2 + 8192 + wave * 512);
      asm volatile("s_waitcnt vmcnt(3)" ::: "memory");  // buf[kt+1] landed
    } else {
      asm volatile("s_waitcnt vmcnt(0)" ::: "memory");
    }
    short8 af[4], bfr[4];
#pragma unroll
    for (int i = 0; i < 4; ++i) {
      const int row = wm + i * 16 + r16;
      const int c   = (q ^ ((row >> 1) & 3)) << 3;
      af[i] = *(const short8*)(const void*)(smem + u0 + row * 32 + c);
    }
#pragma unroll
    for (int j = 0; j < 4; ++j) {
      const int row = wn + j * 16 + r16;
      const int c   = (q ^ ((row >> 1) & 3)) << 3;
      bfr[j] = *(const short8*)(const void*)(smem + u0 + 4096 + row * 32 + c);
    }
    __builtin_amdgcn_s_setprio(1);
#pragma unroll
    for (int i = 0; i < 4; ++i)
#pragma unroll
      for (int j = 0; j < 4; ++j)
        acc[i][j] = __builtin_amdgcn_mfma_f32_16x16x32_bf16(af[i], bfr[j], acc[i][j], 0, 0, 0);
    __builtin_amdgcn_s_setprio(0);

    if (kt < 15) {
      asm volatile("s_waitcnt lgkmcnt(0)" ::: "memory");
      FENCE_BARRIER();
    }
    const int tmp = u0; u0 = u1; u1 = u2; u2 = tmp;
  }
  __syncthreads();

  float* redf = (float*)(smem + 36864);
  float* Sbuf = (float*)(smem + 37888);

  float pj[4];
  if (g == 0) {
    float sj[4];
#pragma unroll
    for (int j = 0; j < 4; ++j) {
      float a = 0.0f;
#pragma unroll
      for (int i = 0; i < 4; ++i)
#pragma unroll
        for (int r = 0; r < 4; ++r)
          a += acc[i][j][r];
      a += __shfl_xor(a, 16, 64);
      a += __shfl_xor(a, 32, 64);
      sj[j] = a;
    }
    __syncthreads();
    if (q == 0) {
#pragma unroll
      for (int j = 0; j < 4; ++j) redf[wave * 64 + j * 16 + r16] = sj[j];
    }
    __syncthreads();
    if (t < 256)
      Sbuf[t] = redf[(2 * (t >> 6)) * 64 + (t & 63)] +
                redf[(2 * (t >> 6) + 1) * 64 + (t & 63)];
    __syncthreads();
#pragma unroll
    for (int j = 0; j < 4; ++j) {
      const int col = wn + j * 16 + r16;
      const float bv = b2[nb * 256 + col];
      const float Sv = Sbuf[col];
      float a = 0.0f;
#pragma unroll
      for (int i = 0; i < 4; ++i)
#pragma unroll
        for (int r = 0; r < 4; ++r)
          a += fmaxf((Sv + acc[i][j][r]) * (1.0f / 129.0f) + bv, 0.0f);
      a += __shfl_xor(a, 16, 64);
      a += __shfl_xor(a, 32, 64);
      pj[j] = a;
    }
    __syncthreads();
  } else {
#pragma unroll
    for (int j = 0; j < 4; ++j) {
      const float bv = b2[nb * 256 + wn + j * 16 + r16];
      float a = 0.0f;
#pragma unroll
      for (int i = 0; i < 4; ++i)
#pragma unroll
        for (int r = 0; r < 4; ++r)
          a += fmaxf(acc[i][j][r] + bv, 0.0f);
      a += __shfl_xor(a, 16, 64);
      a += __shfl_xor(a, 32, 64);
      pj[j] = a;
    }
    __syncthreads();
  }
  if (q == 0) {
#pragma unroll
    for (int j = 0; j < 4; ++j) redf[wave * 64 + j * 16 + r16] = pj[j];
  }
  __syncthreads();
  if (t < 256)
    P[(size_t)g * 512 + nb * 256 + t] =
        (redf[(2 * (t >> 6)) * 64 + (t & 63)] +
         redf[(2 * (t >> 6) + 1) * 64 + (t & 63)]) * (1.0f / 128.0f);
}

// out[m][:] = P[m][:] @ Wf + bfv
__global__ void final_out(const float* __restrict__ P,
                          const float* __restrict__ Wf,
                          const float* __restrict__ bfv,
                          float* __restrict__ out) {
  const int m = blockIdx.x;
  const int l = threadIdx.x;
  float acc[10];
#pragma unroll
  for (int o = 0; o < 10; ++o) acc[o] = 0.0f;
  for (int c = l; c < 512; c += 64) {
    const float p = P[m * 512 + c];
#pragma unroll
    for (int o = 0; o < 10; ++o) acc[o] += p * Wf[c * 10 + o];
  }
#pragma unroll
  for (int off = 32; off; off >>= 1)
#pragma unroll
    for (int o = 0; o < 10; ++o) acc[o] += __shfl_down(acc[o], off, 64);
  if (l == 0) {
#pragma unroll
    for (int o = 0; o < 10; ++o) out[m * 10 + o] = acc[o] + bfv[o];
  }
}

// ===========================================================================
// R9 fused kernel (verified) — fallback when workspace can't hold H1.
// ===========================================================================
__global__ __launch_bounds__(1024) void fused_gcn(
    const float* __restrict__ x,
    const __hip_bfloat16* __restrict__ W1t,
    const __hip_bfloat16* __restrict__ W2t,
    const float* __restrict__ b1,
    const float* __restrict__ b2,
    const float* __restrict__ Wf,
    const float* __restrict__ bfv,
    float* __restrict__ out)
{
  __shared__ __align__(16) __hip_bfloat16 smem[81920];

  const int t  = threadIdx.x;
  const int g  = blockIdx.x;
  const int wave = t >> 6;
  const int l    = t & 63;
  const int q    = l >> 4;
  const int r16  = l & 15;
  const int wm   = (wave & 1) * 64;
  const int wn   = (wave >> 1) * 64;

  const int arow = t >> 3;
  const int kq   = t & 7;
  const float* ga = x + ((size_t)g * 128 + arow) * 512 + kq * 4;
  const int awoff = arow * 32 + (((kq >> 1) ^ ((arow >> 1) & 3)) << 3) + (kq & 1) * 4;

  const int brow = t >> 2;
  const int bgc  = (t & 3) ^ ((brow >> 1) & 3);
  const size_t boff = (size_t)brow * 512 + bgc * 8;
  const __hip_bfloat16* g1b0 = W1t + boff;
  const __hip_bfloat16* g1b1 = g1b0 + (size_t)256 * 512;

  f32x4 acc[4][4];
#pragma unroll
  for (int i = 0; i < 4; ++i)
#pragma unroll
    for (int j = 0; j < 4; ++j)
      acc[i][j] = (f32x4)0.0f;

  {
    f32x4 a0 = *(const f32x4*)(const void*)ga;
    gload_lds16(g1b0, smem + 49152 + wave * 512);
    gload_lds16(g1b1, smem + 49152 + 8192 + wave * 512);
    uint2v w;
    w[0] = pack2_bf16(a0[0], a0[1]);
    w[1] = pack2_bf16(a0[2], a0[3]);
    *(uint2v*)(void*)(smem + awoff) = w;
  }
  for (int kt = 0; kt < 16; ++kt) {
    const int cur = kt & 1;
    const int nxt = cur ^ 1;
    __syncthreads();

    f32x4 aN;
    if (kt < 15) {
      const int ko = (kt + 1) * 32;
      aN = *(const f32x4*)(const void*)(ga + ko);
      gload_lds16(g1b0 + ko, smem + 49152 + nxt * 16384 + wave * 512);
      gload_lds16(g1b1 + ko, smem + 49152 + nxt * 16384 + 8192 + wave * 512);
    }

    short8 af[4], bfr[4];
#pragma unroll
    for (int i = 0; i < 4; ++i) {
      const int row = wm + i * 16 + r16;
      const int c   = (q ^ ((row >> 1) & 3)) << 3;
      af[i] = *(const short8*)(const void*)(smem + cur * 4096 + row * 32 + c);
    }
#pragma unroll
    for (int j = 0; j < 4; ++j) {
      const int row = wn + j * 16 + r16;
      const int c   = (q ^ ((row >> 1) & 3)) << 3;
      bfr[j] = *(const short8*)(const void*)(smem + 49152 + cur * 16384 + row * 32 + c);
    }
#pragma unroll
    for (int i = 0; i < 4; ++i)
#pragma unroll
      for (int j = 0; j < 4; ++j)
        acc[i][j] = __builtin_amdgcn_mfma_f32_16x16x32_bf16(af[i], bfr[j], acc[i][j], 0, 0, 0);

    if (kt < 15) {
      uint2v w;
      w[0] = pack2_bf16(aN[0], aN[1]);
      w[1] = pack2_bf16(aN[2], aN[3]);
      *(uint2v*)(void*)(smem + nxt * 4096 + awoff) = w;
    }
  }
  __syncthreads();

  const __hip_bfloat16* g2b0 = W2t + boff;
  const __hip_bfloat16* g2b1 = g2b0 + (size_t)256 * 512;
  gload_lds16(g2b0, smem + 65536 + wave * 512);

  float* redf = (float*)(smem + 73728);
  float* Sbuf = (float*)(smem + 75776);

  if (g == 0) {
    float sj[4];
#pragma unroll
    for (int j = 0; j < 4; ++j) {
      float a = 0.0f;
#pragma unroll
      for (int i = 0; i < 4; ++i)
#pragma unroll
        for (int r = 0; r < 4; ++r)
          a += acc[i][j][r];
      a += __shfl_xor(a, 16, 64);
      a += __shfl_xor(a, 32, 64);
      sj[j] = a;
    }
    if (q == 0) {
#pragma unroll
      for (int j = 0; j < 4; ++j) redf[wave * 64 + j * 16 + r16] = sj[j];
    }
    __syncthreads();
    if (t < 512)
      Sbuf[t] = redf[((t >> 6) * 2) * 64 + (t & 63)] +
                redf[((t >> 6) * 2 + 1) * 64 + (t & 63)];
    __syncthreads();
#pragma unroll
    for (int j = 0; j < 4; ++j) {
      const int col = wn + j * 16 + r16;
      const float bv = b1[col];
      const float Sv = Sbuf[col];
#pragma unroll
      for (int i = 0; i < 4; ++i)
#pragma unroll
        for (int r = 0; r < 4; ++r) {
          const int row = wm + i * 16 + q * 4 + r;
          const float v = fmaxf((Sv + acc[i][j][r]) * (1.0f / 129.0f) + bv, 0.0f);
          const float o = __shfl_xor(v, 1, 64);
          if ((r16 & 1) == 0) {
            const int sl = (col >> 3) ^ (row & 7);
            *(unsigned int*)(void*)(smem + row * 512 + sl * 8 + (col & 7)) = pack2_bf16(v, o);
          }
        }
    }
  } else {
#pragma unroll
    for (int j = 0; j < 4; ++j) {
      const int col = wn + j * 16 + r16;
      const float bv = b1[col];
#pragma unroll
      for (int i = 0; i < 4; ++i)
#pragma unroll
        for (int r = 0; r < 4; ++r) {
          const int row = wm + i * 16 + q * 4 + r;
          const float v = fmaxf(acc[i][j][r] + bv, 0.0f);
          const float o = __shfl_xor(v, 1, 64);
          if ((r16 & 1) == 0) {
            const int sl = (col >> 3) ^ (row & 7);
            *(unsigned int*)(void*)(smem + row * 512 + sl * 8 + (col & 7)) = pack2_bf16(v, o);
          }
        }
    }
  }

#pragma unroll
  for (int i = 0; i < 4; ++i)
#pragma unroll
    for (int j = 0; j < 4; ++j)
      acc[i][j] = (f32x4)0.0f;

  for (int kt = 0; kt < 16; ++kt) {
    __syncthreads();
    gload_lds16(g2b1 + kt * 32, smem + 73728 + wave * 512);
    if (wave < 8) {
      short8 af[4], bfr[4];
#pragma unroll
      for (int i = 0; i < 4; ++i) {
        const int row = wm + i * 16 + r16;
        const int sl  = (kt * 4 + q) ^ (row & 7);
        af[i] = *(const short8*)(const void*)(smem + row * 512 + sl * 8);
      }
#pragma unroll
      for (int j = 0; j < 4; ++j) {
        const int row = wn + j * 16 + r16;
        const int c   = (q ^ ((row >> 1) & 3)) << 3;
        bfr[j] = *(const short8*)(const void*)(smem + 65536 + row * 32 + c);
      }
      __builtin_amdgcn_s_setprio(1);
#pragma unroll
      for (int i = 0; i < 4; ++i)
#pragma unroll
        for (int j = 0; j < 4; ++j)
          acc[i][j] = __builtin_amdgcn_mfma_f32_16x16x32_bf16(af[i], bfr[j], acc[i][j], 0, 0, 0);
      __builtin_amdgcn_s_setprio(0);
    }
    __syncthreads();
    if (kt < 15)
      gload_lds16(g2b0 + (kt + 1) * 32, smem + 65536 + wave * 512);
    if (wave >= 8) {
      short8 af[4], bfr[4];
#pragma unroll
      for (int i = 0; i < 4; ++i) {
        const int row = wm + i * 16 + r16;
        const int sl  = (kt * 4 + q) ^ (row & 7);
        af[i] = *(const short8*)(const void*)(smem + row * 512 + sl * 8);
      }
#pragma unroll
      for (int j = 0; j < 4; ++j) {
        const int row = wn + j * 16 + r16;
        const int c   = (q ^ ((row >> 1) & 3)) << 3;
        bfr[j] = *(const short8*)(const void*)(smem + 65536 + row * 32 + c);
      }
      __builtin_amdgcn_s_setprio(1);
#pragma unroll
      for (int i = 0; i < 4; ++i)
#pragma unroll
        for (int j = 0; j < 4; ++j)
          acc[i][j] = __builtin_amdgcn_mfma_f32_16x16x32_bf16(af[i], bfr[j], acc[i][j], 0, 0, 0);
      __builtin_amdgcn_s_setprio(0);
    }
  }
  __syncthreads();

  float pj[4];
  if (g == 0) {
    float sj[4];
#pragma unroll
    for (int j = 0; j < 4; ++j) {
      float a = 0.0f;
#pragma unroll
      for (int i = 0; i < 4; ++i)
#pragma unroll
        for (int r = 0; r < 4; ++r)
          a += acc[i][j][r];
      a += __shfl_xor(a, 16, 64);
      a += __shfl_xor(a, 32, 64);
      sj[j] = a;
    }
    if (q == 0) {
#pragma unroll
      for (int j = 0; j < 4; ++j) redf[wave * 64 + j * 16 + r16] = sj[j];
    }
    __syncthreads();
    if (t < 512)
      Sbuf[t] = redf[((t >> 6) * 2) * 64 + (t & 63)] +
                redf[((t >> 6) * 2 + 1) * 64 + (t & 63)];
    __syncthreads();
#pragma unroll
    for (int j = 0; j < 4; ++j) {
      const float bv = b2[wn + j * 16 + r16];
      const float Sv = Sbuf[wn + j * 16 + r16];
      float a = 0.0f;
#pragma unroll
      for (int i = 0; i < 4; ++i)
#pragma unroll
        for (int r = 0; r < 4; ++r)
          a += fmaxf((Sv + acc[i][j][r]) * (1.0f / 129.0f) + bv, 0.0f);
      a += __shfl_xor(a, 16, 64);
      a += __shfl_xor(a, 32, 64);
      pj[j] = a;
    }
  } else {
#pragma unroll
    for (int j = 0; j < 4; ++j) {
      const float bv = b2[wn + j * 16 + r16];
      float a = 0.0f;
#pragma unroll
      for (int i = 0; i < 4; ++i)
#pragma unroll
        for (int r = 0; r < 4; ++r)
          a += fmaxf(acc[i][j][r] + bv, 0.0f);
      a += __shfl_xor(a, 16, 64);
      a += __shfl_xor(a, 32, 64);
      pj[j] = a;
    }
  }
  if (q == 0) {
#pragma unroll
    for (int j = 0; j < 4; ++j) redf[wave * 64 + j * 16 + r16] = pj[j];
  }
  __syncthreads();
  if (t < 512)
    Sbuf[t] =
        (redf[((t >> 6) * 2) * 64 + (t & 63)] +
         redf[((t >> 6) * 2 + 1) * 64 + (t & 63)]) * (1.0f / 128.0f);
  __syncthreads();

  if (wave < 10) {
    float s = 0.0f;
    for (int c = l; c < 512; c += 64) s += Sbuf[c] * Wf[c * 10 + wave];
#pragma unroll
    for (int off = 32; off; off >>= 1) s += __shfl_down(s, off, 64);
    if (l == 0) out[(size_t)g * 10 + wave] = s + bfv[wave];
  }
}

// prep: blocks 0..511 transpose W1/W2 -> bf16 [n][k]; blocks 512..1023 fold
// Wf = W3@Wlin, bfv = b3@Wlin + blin.
__global__ __launch_bounds__(1024) void prep(
    const float* __restrict__ W1, const float* __restrict__ W2,
    unsigned short* __restrict__ W1t, unsigned short* __restrict__ W2t,
    const float* __restrict__ W3, const float* __restrict__ Wlin,
    const float* __restrict__ b3, const float* __restrict__ blin,
    float* __restrict__ Wf, float* __restrict__ bfv) {
  const int b = blockIdx.x;
  if (b < 512) {
    __shared__ float tile[32][33];
    const int z  = b >> 8;
    const int by = (b >> 4) & 15;
    const int bx = b & 15;
    const float* W = z ? W2 : W1;
    unsigned short* Wt = z ? W2t : W1t;
    const int tx = threadIdx.x & 31;
    const int ty = threadIdx.x >> 5;
    tile[ty][tx] = W[(by * 32 + ty) * 512 + bx * 32 + tx];
    __syncthreads();
    Wt[(bx * 32 + ty) * 512 + by * 32 + tx] = bf16_rne(tile[tx][ty]);
  } else {
    const int c = b - 512;
    const int l = threadIdx.x;
    if (l < 64) {
      float acc[10];
#pragma unroll
      for (int o = 0; o < 10; ++o) acc[o] = 0.0f;
      for (int n = l; n < 512; n += 64) {
        const float wv = W3[c * 512 + n];
#pragma unroll
        for (int o = 0; o < 10; ++o) acc[o] += wv * Wlin[n * 10 + o];
      }
#pragma unroll
      for (int off = 32; off; off >>= 1)
#pragma unroll
        for (int o = 0; o < 10; ++o) acc[o] += __shfl_down(acc[o], off, 64);
      if (l == 0) {
#pragma unroll
        for (int o = 0; o < 10; ++o) Wf[c * 10 + o] = acc[o];
      }
      if (c < 10) {
        float s = 0.0f;
        for (int k = l; k < 512; k += 64) s += b3[k] * Wlin[k * 10 + c];
#pragma unroll
        for (int off = 32; off; off >>= 1) s += __shfl_down(s, off, 64);
        if (l == 0) bfv[c] = s + blin[c];
      }
    }
  }
}

extern "C" void kernel_launch(void* const* d_in, const int* in_sizes, int n_in,
                              void* d_out, int out_size, void* d_ws, size_t ws_size,
                              hipStream_t stream) {
  const float* x    = (const float*)d_in[0];
  const float* W1   = (const float*)d_in[1];
  const float* b1   = (const float*)d_in[2];
  const float* W2   = (const float*)d_in[3];
  const float* b2   = (const float*)d_in[4];
  const float* W3   = (const float*)d_in[5];
  const float* b3   = (const float*)d_in[6];
  const float* Wlin = (const float*)d_in[7];
  const float* blin = (const float*)d_in[8];
  float* out = (float*)d_out;

  char* ws = (char*)d_ws;
  unsigned short* W1t = (unsigned short*)ws;                 // 512 KB
  unsigned short* W2t = W1t + 512 * 512;                     // 512 KB
  float* Wf           = (float*)(W2t + 512 * 512);           // 20 KB
  float* bfv          = Wf + 512 * 10;                       // 64 B
  float* P            = bfv + 16;                            // 1 MB
  unsigned short* H1  = (unsigned short*)(P + 512 * 512);    // 64 MB

  const size_t need = (size_t)512 * 512 * 2 * 2 +            // W1t, W2t
                      (512 * 10 + 16 + 512 * 512) * 4 +      // Wf, bfv, P
                      (size_t)65536 * 512 * 2;               // H1

  const bool split = ws_size >= need;

  prep<<<1024, 1024, 0, stream>>>(
      W1, W2, W1t, W2t, W3, Wlin, b3, blin, Wf, bfv);

  if (split) {
    gemm1<<<1024, 512, 0, stream>>>(x, (const __hip_bfloat16*)W1t, b1, H1);
    gemm2<<<1024, 512, 0, stream>>>(H1, (const __hip_bfloat16*)W2t, b2, P);
    final_out<<<512, 64, 0, stream>>>(P, Wf, bfv, out);
  } else {
    fused_gcn<<<512, 1024, 0, stream>>>(
        x, (const __hip_bfloat16*)W1t, (const __hip_bfloat16*)W2t, b1, b2, Wf, bfv, out);
  }
}